// Round 4
// baseline (199.101 us; speedup 1.0000x reference)
//
#include <hip/hip_runtime.h>
#include <hip/hip_cooperative_groups.h>

namespace cg = cooperative_groups;

// SASA fused cooperative kernel, v2. B=2, CIN=192, HW=3136, 6 heads x d=32, 7x7 win.
// R3 failed: cooperative launch with grid=512 + 53KB LDS likely exceeded co-residency
// validation (runtime may account 64KB LDS/CU -> 1 block/CU -> max 256 blocks).
// Fixes: grid=256, check launch rc, fall back to 3 plain kernels on failure.
//
// ws layout (bytes):
//   QK   [6272][384] bf16 @ 0        q ch 0-191 | k ch 192-383
//   V    [6272][192] f32  @ 4816896  fp32 to protect output accuracy
//   OACT [6272][192] bf16 @ 9633792  attention out = proj B-operand

#define HW    3136
#define WIMG  56
#define CIN   192
#define QKLD  384
#define SMEM_BYTES 53312

using short8 = __attribute__((ext_vector_type(8))) short;
using f32x4  = __attribute__((ext_vector_type(4))) float;

__device__ __forceinline__ unsigned short f2bf(float f) {
    union { float f; unsigned u; } v; v.f = f;
    unsigned r = v.u + 0x7fffu + ((v.u >> 16) & 1u);
    return (unsigned short)(r >> 16);
}
__device__ __forceinline__ unsigned pack2(float a, float b) {
    return (unsigned)f2bf(a) | ((unsigned)f2bf(b) << 16);
}
__device__ __forceinline__ float bflo(unsigned u) {
    union { unsigned u; float f; } v; v.u = u << 16; return v.f;
}
__device__ __forceinline__ float bfhi(unsigned u) {
    union { unsigned u; float f; } v; v.u = u & 0xffff0000u; return v.f;
}

// ======================= Phase 1: QKV GEMM tile =============================
// t in [0,882): mt = t%98 (64-pixel strip over b,p), nt = t/98 (64 of 576 out ch).
// A: transpose x[b][c][p] fp32 -> As[p][c] bf16 in staging. B: W rows -> bf16.
__device__ __forceinline__ void phase1_qkv(
    int t, int tid, const float* __restrict__ x, const float* __restrict__ wq,
    const float* __restrict__ wk, const float* __restrict__ wv,
    unsigned short* __restrict__ qk, float* __restrict__ vv, char* smem)
{
    unsigned short* As  = (unsigned short*)smem;     // 64 x 200 ushorts
    unsigned short* Bs  = As + 64 * 200;
    unsigned*       Asw = (unsigned*)smem;           // dword view, row stride 100
    unsigned*       Bsw = (unsigned*)(smem + 25600);

    const int lane = tid & 63, wave = tid >> 6;
    const int l15  = lane & 15, quad = lane >> 4;
    const int wm   = (wave & 1) * 32, wn = (wave >> 1) * 32;

    const int mt = t % 98, nt = t / 98;
    const int m0 = mt * 64, n0 = nt * 64;
    const float* Wp = (nt < 3) ? (wq + (size_t)n0 * CIN)
                    : (nt < 6) ? (wk + (size_t)(n0 - 192) * CIN)
                               : (wv + (size_t)(n0 - 384) * CIN);

    #pragma unroll
    for (int i = 0; i < 6; ++i) {
        int u = tid + 256 * i;
        int pq = u & 15, c2 = u >> 4;            // pq: p-quad 0..15, c2: 0..95
        int pp = m0 + pq * 4;
        int bb = (pp >= HW) ? 1 : 0;
        const float* src = x + ((size_t)(bb * CIN + c2 * 2)) * HW + (pp - bb * HW);
        float4 f0 = *(const float4*)src;          // c = c2*2,   p..p+3
        float4 f1 = *(const float4*)(src + HW);   // c = c2*2+1, p..p+3
        Asw[(pq * 4 + 0) * 100 + c2] = pack2(f0.x, f1.x);
        Asw[(pq * 4 + 1) * 100 + c2] = pack2(f0.y, f1.y);
        Asw[(pq * 4 + 2) * 100 + c2] = pack2(f0.z, f1.z);
        Asw[(pq * 4 + 3) * 100 + c2] = pack2(f0.w, f1.w);
    }
    {
        int o = tid >> 2, c4 = tid & 3;
        #pragma unroll
        for (int i = 0; i < 12; ++i) {
            int cq = c4 + 4 * i;                 // 0..47
            float4 w = *(const float4*)(Wp + (size_t)o * CIN + cq * 4);
            uint2 d; d.x = pack2(w.x, w.y); d.y = pack2(w.z, w.w);
            *(uint2*)(Bsw + o * 100 + cq * 2) = d;
        }
    }
    __syncthreads();

    f32x4 acc[2][2] = {};
    const unsigned short* pa0 = As + (wm + l15) * 200 + quad * 8;
    const unsigned short* pb0 = Bs + (wn + l15) * 200 + quad * 8;
    #pragma unroll
    for (int s = 0; s < 6; ++s) {
        short8 a0 = *(const short8*)(pa0 + s * 32);
        short8 a1 = *(const short8*)(pa0 + 16 * 200 + s * 32);
        short8 b0 = *(const short8*)(pb0 + s * 32);
        short8 b1 = *(const short8*)(pb0 + 16 * 200 + s * 32);
        acc[0][0] = __builtin_amdgcn_mfma_f32_16x16x32_bf16(a0, b0, acc[0][0], 0, 0, 0);
        acc[0][1] = __builtin_amdgcn_mfma_f32_16x16x32_bf16(a0, b1, acc[0][1], 0, 0, 0);
        acc[1][0] = __builtin_amdgcn_mfma_f32_16x16x32_bf16(a1, b0, acc[1][0], 0, 0, 0);
        acc[1][1] = __builtin_amdgcn_mfma_f32_16x16x32_bf16(a1, b1, acc[1][1], 0, 0, 0);
    }

    const int gm = m0 + wm + quad * 4;   // global pixel row
    const int gn = n0 + wn + l15;        // output channel (0..575)
    if (nt < 6) {
        #pragma unroll
        for (int ti = 0; ti < 2; ++ti)
            #pragma unroll
            for (int tj = 0; tj < 2; ++tj)
                #pragma unroll
                for (int rr = 0; rr < 4; ++rr)
                    qk[(size_t)(gm + ti * 16 + rr) * QKLD + (gn + tj * 16)] =
                        f2bf(acc[ti][tj][rr]);
    } else {
        #pragma unroll
        for (int ti = 0; ti < 2; ++ti)
            #pragma unroll
            for (int tj = 0; tj < 2; ++tj)
                #pragma unroll
                for (int rr = 0; rr < 4; ++rr)
                    vv[(size_t)(gm + ti * 16 + rr) * CIN + (gn + tj * 16 - 384)] =
                        acc[ti][tj][rr];
    }
}

// ======================= Phase 2: windowed attention ========================
// t in [0,588): 49 8x8-pixel tiles x 12 (b,h). 4 threads/pixel (d split 4x8).
__device__ __forceinline__ void phase2_attn(
    int t, int tid, const unsigned short* __restrict__ qk,
    const float* __restrict__ vv, const float* __restrict__ pos,
    unsigned short* __restrict__ oact, char* smem)
{
    float* kbuf = (float*)smem;          // [196 px][32 ch] stride 34 floats
    float* vbuf = kbuf + 6664;

    const int tz = t / 49, r49 = t - tz * 49;
    const int ty = r49 / 7, tx = r49 - ty * 7;
    const int bq = tz / 6, h = tz - bq * 6;
    const int y0 = ty * 8 - 3, x0 = tx * 8 - 3;

    #pragma unroll
    for (int i = 0; i < 4; ++i) {
        int u = tid + 256 * i;
        if (u < 784) {
            int pp = u >> 2, uu = u & 3;
            int py = pp / 14, px = pp - py * 14;
            int gy = y0 + py, gx = x0 + px;
            float f0=0,f1=0,f2=0,f3=0,f4=0,f5=0,f6=0,f7=0;
            if ((unsigned)gy < 56u && (unsigned)gx < 56u) {
                uint4 rv = *(const uint4*)(qk +
                    (size_t)(bq * HW + gy * WIMG + gx) * QKLD + 192 + h * 32 + uu * 8);
                f0=bflo(rv.x); f1=bfhi(rv.x); f2=bflo(rv.y); f3=bfhi(rv.y);
                f4=bflo(rv.z); f5=bfhi(rv.z); f6=bflo(rv.w); f7=bfhi(rv.w);
            }
            float* dst = kbuf + pp * 34 + uu * 8;
            *(float2*)(dst + 0) = make_float2(f0, f1);
            *(float2*)(dst + 2) = make_float2(f2, f3);
            *(float2*)(dst + 4) = make_float2(f4, f5);
            *(float2*)(dst + 6) = make_float2(f6, f7);
        }
    }
    #pragma unroll
    for (int i = 0; i < 7; ++i) {
        int u = tid + 256 * i;
        if (u < 1568) {
            int pp = u >> 3, uu = u & 7;
            int py = pp / 14, px = pp - py * 14;
            int gy = y0 + py, gx = x0 + px;
            float4 val = make_float4(0.f, 0.f, 0.f, 0.f);
            if ((unsigned)gy < 56u && (unsigned)gx < 56u)
                val = *(const float4*)(vv +
                    (size_t)(bq * HW + gy * WIMG + gx) * CIN + h * 32 + uu * 4);
            float* dst = vbuf + pp * 34 + uu * 4;
            *(float2*)(dst + 0) = make_float2(val.x, val.y);
            *(float2*)(dst + 2) = make_float2(val.z, val.w);
        }
    }
    __syncthreads();

    const int sub = tid & 3, pix = tid >> 2;
    const int py = pix >> 3, px = pix & 7;
    const int y = ty * 8 + py, xx = tx * 8 + px;
    const int p = y * WIMG + xx;

    uint4 qv = *(const uint4*)(qk + (size_t)(bq * HW + p) * QKLD + h * 32 + sub * 8);
    float q0=bflo(qv.x), q1=bfhi(qv.x), q2=bflo(qv.y), q3=bfhi(qv.y);
    float q4=bflo(qv.z), q5=bfhi(qv.z), q6=bflo(qv.w), q7=bfhi(qv.w);

    float posr[13];
    #pragma unroll
    for (int i = 0; i < 13; ++i) posr[i] = pos[i];

    float logits[49];
    #pragma unroll
    for (int kk = 0; kk < 49; ++kk) {
        const int ky = kk / 7, kx = kk % 7;
        const int pp = (py + ky) * 14 + (px + kx);
        const float2* kp = (const float2*)(kbuf + pp * 34 + sub * 8);
        float2 k0 = kp[0], k1 = kp[1], k2 = kp[2], k3 = kp[3];
        float s = 0.f;
        s = fmaf(q0, k0.x, s); s = fmaf(q1, k0.y, s);
        s = fmaf(q2, k1.x, s); s = fmaf(q3, k1.y, s);
        s = fmaf(q4, k2.x, s); s = fmaf(q5, k2.y, s);
        s = fmaf(q6, k3.x, s); s = fmaf(q7, k3.y, s);
        s += __shfl_xor(s, 1);
        s += __shfl_xor(s, 2);
        logits[kk] = s + posr[ky + kx];
    }

    float m = logits[0];
    #pragma unroll
    for (int kk = 1; kk < 49; ++kk) m = fmaxf(m, logits[kk]);
    float sum = 0.f;
    #pragma unroll
    for (int kk = 0; kk < 49; ++kk) {
        logits[kk] = __expf(logits[kk] - m);
        sum += logits[kk];
    }
    const float inv = 1.f / sum;

    float a0=0,a1=0,a2=0,a3=0,a4=0,a5=0,a6=0,a7=0;
    #pragma unroll
    for (int kk = 0; kk < 49; ++kk) {
        const int ky = kk / 7, kx = kk % 7;
        const int pp = (py + ky) * 14 + (px + kx);
        const float2* vp = (const float2*)(vbuf + pp * 34 + sub * 8);
        float2 v0 = vp[0], v1 = vp[1], v2 = vp[2], v3 = vp[3];
        const float pw = logits[kk] * inv;
        a0 = fmaf(pw, v0.x, a0); a1 = fmaf(pw, v0.y, a1);
        a2 = fmaf(pw, v1.x, a2); a3 = fmaf(pw, v1.y, a3);
        a4 = fmaf(pw, v2.x, a4); a5 = fmaf(pw, v2.y, a5);
        a6 = fmaf(pw, v3.x, a6); a7 = fmaf(pw, v3.y, a7);
    }

    ushort4 h0, h1;
    h0.x = f2bf(a0); h0.y = f2bf(a1); h0.z = f2bf(a2); h0.w = f2bf(a3);
    h1.x = f2bf(a4); h1.y = f2bf(a5); h1.z = f2bf(a6); h1.w = f2bf(a7);
    unsigned short* ob = oact + (size_t)(bq * HW + p) * CIN + h * 32 + sub * 8;
    *(ushort4*)ob       = h0;
    *(ushort4*)(ob + 4) = h1;
}

// ======================= Phase 3: projection tile ===========================
// t in [0,294): mt = t%3 (64 out ch), pt = t/3 (64-pixel strip).
__device__ __forceinline__ void phase3_proj(
    int t, int tid, const float* __restrict__ wproj,
    const unsigned short* __restrict__ oact, float* __restrict__ out, char* smem)
{
    unsigned short* As  = (unsigned short*)smem;
    unsigned short* Bs  = As + 64 * 200;
    unsigned*       Asw = (unsigned*)smem;

    const int lane = tid & 63, wave = tid >> 6;
    const int l15  = lane & 15, quad = lane >> 4;
    const int wm   = (wave & 1) * 32, wn = (wave >> 1) * 32;

    const int mt = t % 3, pt = t / 3;
    {
        int o = tid >> 2, c4 = tid & 3;
        #pragma unroll
        for (int i = 0; i < 12; ++i) {
            int cq = c4 + 4 * i;
            float4 w = *(const float4*)(wproj + (size_t)(mt * 64 + o) * CIN + cq * 4);
            uint2 d; d.x = pack2(w.x, w.y); d.y = pack2(w.z, w.w);
            *(uint2*)(Asw + o * 100 + cq * 2) = d;
        }
    }
    {
        int rw = tid >> 2, s4 = tid & 3;
        #pragma unroll
        for (int i = 0; i < 6; ++i) {
            int seg = s4 + 4 * i;               // 0..23
            uint4 dv = *(const uint4*)(oact + (size_t)(pt * 64 + rw) * CIN + seg * 8);
            *(uint4*)(Bs + rw * 200 + seg * 8) = dv;
        }
    }
    __syncthreads();

    f32x4 acc[2][2] = {};
    const unsigned short* pa0 = As + (wm + l15) * 200 + quad * 8;
    const unsigned short* pb0 = Bs + (wn + l15) * 200 + quad * 8;
    #pragma unroll
    for (int s = 0; s < 6; ++s) {
        short8 a0 = *(const short8*)(pa0 + s * 32);
        short8 a1 = *(const short8*)(pa0 + 16 * 200 + s * 32);
        short8 b0 = *(const short8*)(pb0 + s * 32);
        short8 b1 = *(const short8*)(pb0 + 16 * 200 + s * 32);
        acc[0][0] = __builtin_amdgcn_mfma_f32_16x16x32_bf16(a0, b0, acc[0][0], 0, 0, 0);
        acc[0][1] = __builtin_amdgcn_mfma_f32_16x16x32_bf16(a0, b1, acc[0][1], 0, 0, 0);
        acc[1][0] = __builtin_amdgcn_mfma_f32_16x16x32_bf16(a1, b0, acc[1][0], 0, 0, 0);
        acc[1][1] = __builtin_amdgcn_mfma_f32_16x16x32_bf16(a1, b1, acc[1][1], 0, 0, 0);
    }

    const int bb = (pt * 64 >= HW) ? 1 : 0;
    const int pl = pt * 64 - bb * HW + wn + l15;      // col = pixel within batch
    const int go = mt * 64 + wm + quad * 4;           // row = output channel
    float* Yb = out + (size_t)bb * (CIN * HW);
    #pragma unroll
    for (int ti = 0; ti < 2; ++ti)
        #pragma unroll
        for (int tj = 0; tj < 2; ++tj)
            #pragma unroll
            for (int rr = 0; rr < 4; ++rr)
                Yb[(size_t)(go + ti * 16 + rr) * HW + pl + tj * 16] = acc[ti][tj][rr];
}

// ======================= kernels ============================================
__global__ __launch_bounds__(256) void fused_sasa(
    const float* __restrict__ x, const float* __restrict__ wq,
    const float* __restrict__ wk, const float* __restrict__ wv,
    const float* __restrict__ wproj, const float* __restrict__ pos,
    unsigned short* __restrict__ qk, float* __restrict__ vv,
    unsigned short* __restrict__ oact, float* __restrict__ out)
{
    extern __shared__ char smem[];
    cg::grid_group grid = cg::this_grid();
    const int tid = threadIdx.x, nb = gridDim.x;

    for (int t = blockIdx.x; t < 882; t += nb) {
        phase1_qkv(t, tid, x, wq, wk, wv, qk, vv, smem);
        __syncthreads();
    }
    grid.sync();
    for (int t = blockIdx.x; t < 588; t += nb) {
        phase2_attn(t, tid, qk, vv, pos, oact, smem);
        __syncthreads();
    }
    grid.sync();
    for (int t = blockIdx.x; t < 294; t += nb) {
        phase3_proj(t, tid, wproj, oact, out, smem);
        __syncthreads();
    }
}

__global__ __launch_bounds__(256) void k_p1(
    const float* __restrict__ x, const float* __restrict__ wq,
    const float* __restrict__ wk, const float* __restrict__ wv,
    unsigned short* __restrict__ qk, float* __restrict__ vv)
{
    extern __shared__ char smem[];
    phase1_qkv(blockIdx.x, threadIdx.x, x, wq, wk, wv, qk, vv, smem);
}

__global__ __launch_bounds__(256) void k_p2(
    const unsigned short* __restrict__ qk, const float* __restrict__ vv,
    const float* __restrict__ pos, unsigned short* __restrict__ oact)
{
    extern __shared__ char smem[];
    phase2_attn(blockIdx.x, threadIdx.x, qk, vv, pos, oact, smem);
}

__global__ __launch_bounds__(256) void k_p3(
    const float* __restrict__ wproj, const unsigned short* __restrict__ oact,
    float* __restrict__ out)
{
    extern __shared__ char smem[];
    phase3_proj(blockIdx.x, threadIdx.x, wproj, oact, out, smem);
}

// ---------------------------------------------------------------------------
extern "C" void kernel_launch(void* const* d_in, const int* in_sizes, int n_in,
                              void* d_out, int out_size, void* d_ws, size_t ws_size,
                              hipStream_t stream)
{
    const float* x     = (const float*)d_in[0];
    const float* wq    = (const float*)d_in[1];
    const float* wk    = (const float*)d_in[2];
    const float* wv    = (const float*)d_in[3];
    const float* pos   = (const float*)d_in[4];
    const float* wproj = (const float*)d_in[5];

    char* ws = (char*)d_ws;
    unsigned short* qkp   = (unsigned short*)ws;
    float*          vvp   = (float*)(ws + 4816896);
    unsigned short* oactp = (unsigned short*)(ws + 9633792);
    float*          outp  = (float*)d_out;

    void* args[10] = { (void*)&x, (void*)&wq, (void*)&wk, (void*)&wv, (void*)&wproj,
                       (void*)&pos, (void*)&qkp, (void*)&vvp, (void*)&oactp, (void*)&outp };
    hipError_t rc = hipLaunchCooperativeKernel(fused_sasa, dim3(256), dim3(256),
                                               args, (unsigned)SMEM_BYTES, stream);
    if (rc != hipSuccess) {
        (void)hipGetLastError();   // clear sticky error, use plain pipeline
        k_p1<<<dim3(882), dim3(256), SMEM_BYTES, stream>>>(x, wq, wk, wv, qkp, vvp);
        k_p2<<<dim3(588), dim3(256), SMEM_BYTES, stream>>>(qkp, vvp, pos, oactp);
        k_p3<<<dim3(294), dim3(256), SMEM_BYTES, stream>>>(wproj, oactp, outp);
    }
}

// Round 5
// 111.423 us; speedup vs baseline: 1.7869x; 1.7869x over previous
//
#include <hip/hip_runtime.h>

// SASA plain 3-kernel pipeline (R4 fallback path promoted to primary).
// B=2, CIN=192, HW=3136, 6 heads x d=32, 7x7 window.
// R4 lesson: cooperative fusion at grid=256 (co-residency legal) is latency-bound
// (4 waves/CU, MfmaUtil 0.66%) -> 105us. Plain small kernels at 3 blocks/CU run the
// same phases in ~18us. dur_us = kernels + ~95us harness ws-poison (fixed).
//
// ws layout (bytes):
//   QK   [6272][384] bf16 @ 0        q ch 0-191 | k ch 192-383
//   V    [6272][192] f32  @ 4816896  fp32 to protect output accuracy
//   OACT [6272][192] bf16 @ 9633792  attention out = proj B-operand

#define HW    3136
#define WIMG  56
#define CIN   192
#define QKLD  384
#define SMEM_BYTES 53312

using short8 = __attribute__((ext_vector_type(8))) short;
using f32x4  = __attribute__((ext_vector_type(4))) float;

__device__ __forceinline__ unsigned short f2bf(float f) {
    union { float f; unsigned u; } v; v.f = f;
    unsigned r = v.u + 0x7fffu + ((v.u >> 16) & 1u);
    return (unsigned short)(r >> 16);
}
__device__ __forceinline__ unsigned pack2(float a, float b) {
    return (unsigned)f2bf(a) | ((unsigned)f2bf(b) << 16);
}
__device__ __forceinline__ float bflo(unsigned u) {
    union { unsigned u; float f; } v; v.u = u << 16; return v.f;
}
__device__ __forceinline__ float bfhi(unsigned u) {
    union { unsigned u; float f; } v; v.u = u & 0xffff0000u; return v.f;
}

// ======================= Phase 1: QKV GEMM tile =============================
// t in [0,882): mt = t%98 (64-pixel strip over b,p), nt = t/98 (64 of 576 out ch).
// A: transpose x[b][c][p] fp32 -> As[p][c] bf16 in staging. B: W rows -> bf16.
__global__ __launch_bounds__(256) void k_p1(
    const float* __restrict__ x, const float* __restrict__ wq,
    const float* __restrict__ wk, const float* __restrict__ wv,
    unsigned short* __restrict__ qk, float* __restrict__ vv)
{
    extern __shared__ char smem[];
    unsigned short* As  = (unsigned short*)smem;     // 64 x 200 ushorts
    unsigned short* Bs  = As + 64 * 200;
    unsigned*       Asw = (unsigned*)smem;           // dword view, row stride 100
    unsigned*       Bsw = (unsigned*)(smem + 25600);

    const int tid = threadIdx.x;
    const int lane = tid & 63, wave = tid >> 6;
    const int l15  = lane & 15, quad = lane >> 4;
    const int wm   = (wave & 1) * 32, wn = (wave >> 1) * 32;

    const int t = blockIdx.x;
    const int mt = t % 98, nt = t / 98;
    const int m0 = mt * 64, n0 = nt * 64;
    const float* Wp = (nt < 3) ? (wq + (size_t)n0 * CIN)
                    : (nt < 6) ? (wk + (size_t)(n0 - 192) * CIN)
                               : (wv + (size_t)(n0 - 384) * CIN);

    #pragma unroll
    for (int i = 0; i < 6; ++i) {
        int u = tid + 256 * i;
        int pq = u & 15, c2 = u >> 4;            // pq: p-quad 0..15, c2: 0..95
        int pp = m0 + pq * 4;
        int bb = (pp >= HW) ? 1 : 0;
        const float* src = x + ((size_t)(bb * CIN + c2 * 2)) * HW + (pp - bb * HW);
        float4 f0 = *(const float4*)src;          // c = c2*2,   p..p+3
        float4 f1 = *(const float4*)(src + HW);   // c = c2*2+1, p..p+3
        Asw[(pq * 4 + 0) * 100 + c2] = pack2(f0.x, f1.x);
        Asw[(pq * 4 + 1) * 100 + c2] = pack2(f0.y, f1.y);
        Asw[(pq * 4 + 2) * 100 + c2] = pack2(f0.z, f1.z);
        Asw[(pq * 4 + 3) * 100 + c2] = pack2(f0.w, f1.w);
    }
    {
        int o = tid >> 2, c4 = tid & 3;
        #pragma unroll
        for (int i = 0; i < 12; ++i) {
            int cq = c4 + 4 * i;                 // 0..47
            float4 w = *(const float4*)(Wp + (size_t)o * CIN + cq * 4);
            uint2 d; d.x = pack2(w.x, w.y); d.y = pack2(w.z, w.w);
            *(uint2*)(Bsw + o * 100 + cq * 2) = d;
        }
    }
    __syncthreads();

    f32x4 acc[2][2] = {};
    const unsigned short* pa0 = As + (wm + l15) * 200 + quad * 8;
    const unsigned short* pb0 = Bs + (wn + l15) * 200 + quad * 8;
    #pragma unroll
    for (int s = 0; s < 6; ++s) {
        short8 a0 = *(const short8*)(pa0 + s * 32);
        short8 a1 = *(const short8*)(pa0 + 16 * 200 + s * 32);
        short8 b0 = *(const short8*)(pb0 + s * 32);
        short8 b1 = *(const short8*)(pb0 + 16 * 200 + s * 32);
        acc[0][0] = __builtin_amdgcn_mfma_f32_16x16x32_bf16(a0, b0, acc[0][0], 0, 0, 0);
        acc[0][1] = __builtin_amdgcn_mfma_f32_16x16x32_bf16(a0, b1, acc[0][1], 0, 0, 0);
        acc[1][0] = __builtin_amdgcn_mfma_f32_16x16x32_bf16(a1, b0, acc[1][0], 0, 0, 0);
        acc[1][1] = __builtin_amdgcn_mfma_f32_16x16x32_bf16(a1, b1, acc[1][1], 0, 0, 0);
    }

    const int gm = m0 + wm + quad * 4;   // global pixel row
    const int gn = n0 + wn + l15;        // output channel (0..575)
    if (nt < 6) {
        #pragma unroll
        for (int ti = 0; ti < 2; ++ti)
            #pragma unroll
            for (int tj = 0; tj < 2; ++tj)
                #pragma unroll
                for (int rr = 0; rr < 4; ++rr)
                    qk[(size_t)(gm + ti * 16 + rr) * QKLD + (gn + tj * 16)] =
                        f2bf(acc[ti][tj][rr]);
    } else {
        #pragma unroll
        for (int ti = 0; ti < 2; ++ti)
            #pragma unroll
            for (int tj = 0; tj < 2; ++tj)
                #pragma unroll
                for (int rr = 0; rr < 4; ++rr)
                    vv[(size_t)(gm + ti * 16 + rr) * CIN + (gn + tj * 16 - 384)] =
                        acc[ti][tj][rr];
    }
}

// ======================= Phase 2: windowed attention ========================
// t in [0,588): 49 8x8-pixel tiles x 12 (b,h). 4 threads/pixel (d split 4x8).
__global__ __launch_bounds__(256) void k_p2(
    const unsigned short* __restrict__ qk, const float* __restrict__ vv,
    const float* __restrict__ pos, unsigned short* __restrict__ oact)
{
    extern __shared__ char smem[];
    float* kbuf = (float*)smem;          // [196 px][32 ch] stride 34 floats
    float* vbuf = kbuf + 6664;

    const int tid = threadIdx.x;
    const int t = blockIdx.x;
    const int tz = t / 49, r49 = t - tz * 49;
    const int ty = r49 / 7, tx = r49 - ty * 7;
    const int bq = tz / 6, h = tz - bq * 6;
    const int y0 = ty * 8 - 3, x0 = tx * 8 - 3;

    #pragma unroll
    for (int i = 0; i < 4; ++i) {
        int u = tid + 256 * i;
        if (u < 784) {
            int pp = u >> 2, uu = u & 3;
            int py = pp / 14, px = pp - py * 14;
            int gy = y0 + py, gx = x0 + px;
            float f0=0,f1=0,f2=0,f3=0,f4=0,f5=0,f6=0,f7=0;
            if ((unsigned)gy < 56u && (unsigned)gx < 56u) {
                uint4 rv = *(const uint4*)(qk +
                    (size_t)(bq * HW + gy * WIMG + gx) * QKLD + 192 + h * 32 + uu * 8);
                f0=bflo(rv.x); f1=bfhi(rv.x); f2=bflo(rv.y); f3=bfhi(rv.y);
                f4=bflo(rv.z); f5=bfhi(rv.z); f6=bflo(rv.w); f7=bfhi(rv.w);
            }
            float* dst = kbuf + pp * 34 + uu * 8;
            *(float2*)(dst + 0) = make_float2(f0, f1);
            *(float2*)(dst + 2) = make_float2(f2, f3);
            *(float2*)(dst + 4) = make_float2(f4, f5);
            *(float2*)(dst + 6) = make_float2(f6, f7);
        }
    }
    #pragma unroll
    for (int i = 0; i < 7; ++i) {
        int u = tid + 256 * i;
        if (u < 1568) {
            int pp = u >> 3, uu = u & 7;
            int py = pp / 14, px = pp - py * 14;
            int gy = y0 + py, gx = x0 + px;
            float4 val = make_float4(0.f, 0.f, 0.f, 0.f);
            if ((unsigned)gy < 56u && (unsigned)gx < 56u)
                val = *(const float4*)(vv +
                    (size_t)(bq * HW + gy * WIMG + gx) * CIN + h * 32 + uu * 4);
            float* dst = vbuf + pp * 34 + uu * 4;
            *(float2*)(dst + 0) = make_float2(val.x, val.y);
            *(float2*)(dst + 2) = make_float2(val.z, val.w);
        }
    }
    __syncthreads();

    const int sub = tid & 3, pix = tid >> 2;
    const int py = pix >> 3, px = pix & 7;
    const int y = ty * 8 + py, xx = tx * 8 + px;
    const int p = y * WIMG + xx;

    uint4 qv = *(const uint4*)(qk + (size_t)(bq * HW + p) * QKLD + h * 32 + sub * 8);
    float q0=bflo(qv.x), q1=bfhi(qv.x), q2=bflo(qv.y), q3=bfhi(qv.y);
    float q4=bflo(qv.z), q5=bfhi(qv.z), q6=bflo(qv.w), q7=bfhi(qv.w);

    float posr[13];
    #pragma unroll
    for (int i = 0; i < 13; ++i) posr[i] = pos[i];

    float logits[49];
    #pragma unroll
    for (int kk = 0; kk < 49; ++kk) {
        const int ky = kk / 7, kx = kk % 7;
        const int pp = (py + ky) * 14 + (px + kx);
        const float2* kp = (const float2*)(kbuf + pp * 34 + sub * 8);
        float2 k0 = kp[0], k1 = kp[1], k2 = kp[2], k3 = kp[3];
        float s = 0.f;
        s = fmaf(q0, k0.x, s); s = fmaf(q1, k0.y, s);
        s = fmaf(q2, k1.x, s); s = fmaf(q3, k1.y, s);
        s = fmaf(q4, k2.x, s); s = fmaf(q5, k2.y, s);
        s = fmaf(q6, k3.x, s); s = fmaf(q7, k3.y, s);
        s += __shfl_xor(s, 1);
        s += __shfl_xor(s, 2);
        logits[kk] = s + posr[ky + kx];
    }

    float m = logits[0];
    #pragma unroll
    for (int kk = 1; kk < 49; ++kk) m = fmaxf(m, logits[kk]);
    float sum = 0.f;
    #pragma unroll
    for (int kk = 0; kk < 49; ++kk) {
        logits[kk] = __expf(logits[kk] - m);
        sum += logits[kk];
    }
    const float inv = 1.f / sum;

    float a0=0,a1=0,a2=0,a3=0,a4=0,a5=0,a6=0,a7=0;
    #pragma unroll
    for (int kk = 0; kk < 49; ++kk) {
        const int ky = kk / 7, kx = kk % 7;
        const int pp = (py + ky) * 14 + (px + kx);
        const float2* vp = (const float2*)(vbuf + pp * 34 + sub * 8);
        float2 v0 = vp[0], v1 = vp[1], v2 = vp[2], v3 = vp[3];
        const float pw = logits[kk] * inv;
        a0 = fmaf(pw, v0.x, a0); a1 = fmaf(pw, v0.y, a1);
        a2 = fmaf(pw, v1.x, a2); a3 = fmaf(pw, v1.y, a3);
        a4 = fmaf(pw, v2.x, a4); a5 = fmaf(pw, v2.y, a5);
        a6 = fmaf(pw, v3.x, a6); a7 = fmaf(pw, v3.y, a7);
    }

    ushort4 h0, h1;
    h0.x = f2bf(a0); h0.y = f2bf(a1); h0.z = f2bf(a2); h0.w = f2bf(a3);
    h1.x = f2bf(a4); h1.y = f2bf(a5); h1.z = f2bf(a6); h1.w = f2bf(a7);
    unsigned short* ob = oact + (size_t)(bq * HW + p) * CIN + h * 32 + sub * 8;
    *(ushort4*)ob       = h0;
    *(ushort4*)(ob + 4) = h1;
}

// ======================= Phase 3: projection tile ===========================
// t in [0,294): mt = t%3 (64 out ch), pt = t/3 (64-pixel strip).
__global__ __launch_bounds__(256) void k_p3(
    const float* __restrict__ wproj, const unsigned short* __restrict__ oact,
    float* __restrict__ out)
{
    extern __shared__ char smem[];
    unsigned short* As  = (unsigned short*)smem;
    unsigned short* Bs  = As + 64 * 200;
    unsigned*       Asw = (unsigned*)smem;

    const int tid = threadIdx.x;
    const int lane = tid & 63, wave = tid >> 6;
    const int l15  = lane & 15, quad = lane >> 4;
    const int wm   = (wave & 1) * 32, wn = (wave >> 1) * 32;

    const int t = blockIdx.x;
    const int mt = t % 3, pt = t / 3;
    {
        int o = tid >> 2, c4 = tid & 3;
        #pragma unroll
        for (int i = 0; i < 12; ++i) {
            int cq = c4 + 4 * i;
            float4 w = *(const float4*)(wproj + (size_t)(mt * 64 + o) * CIN + cq * 4);
            uint2 d; d.x = pack2(w.x, w.y); d.y = pack2(w.z, w.w);
            *(uint2*)(Asw + o * 100 + cq * 2) = d;
        }
    }
    {
        int rw = tid >> 2, s4 = tid & 3;
        #pragma unroll
        for (int i = 0; i < 6; ++i) {
            int seg = s4 + 4 * i;               // 0..23
            uint4 dv = *(const uint4*)(oact + (size_t)(pt * 64 + rw) * CIN + seg * 8);
            *(uint4*)(Bs + rw * 200 + seg * 8) = dv;
        }
    }
    __syncthreads();

    f32x4 acc[2][2] = {};
    const unsigned short* pa0 = As + (wm + l15) * 200 + quad * 8;
    const unsigned short* pb0 = Bs + (wn + l15) * 200 + quad * 8;
    #pragma unroll
    for (int s = 0; s < 6; ++s) {
        short8 a0 = *(const short8*)(pa0 + s * 32);
        short8 a1 = *(const short8*)(pa0 + 16 * 200 + s * 32);
        short8 b0 = *(const short8*)(pb0 + s * 32);
        short8 b1 = *(const short8*)(pb0 + 16 * 200 + s * 32);
        acc[0][0] = __builtin_amdgcn_mfma_f32_16x16x32_bf16(a0, b0, acc[0][0], 0, 0, 0);
        acc[0][1] = __builtin_amdgcn_mfma_f32_16x16x32_bf16(a0, b1, acc[0][1], 0, 0, 0);
        acc[1][0] = __builtin_amdgcn_mfma_f32_16x16x32_bf16(a1, b0, acc[1][0], 0, 0, 0);
        acc[1][1] = __builtin_amdgcn_mfma_f32_16x16x32_bf16(a1, b1, acc[1][1], 0, 0, 0);
    }

    const int bb = (pt * 64 >= HW) ? 1 : 0;
    const int pl = pt * 64 - bb * HW + wn + l15;      // col = pixel within batch
    const int go = mt * 64 + wm + quad * 4;           // row = output channel
    float* Yb = out + (size_t)bb * (CIN * HW);
    #pragma unroll
    for (int ti = 0; ti < 2; ++ti)
        #pragma unroll
        for (int tj = 0; tj < 2; ++tj)
            #pragma unroll
            for (int rr = 0; rr < 4; ++rr)
                Yb[(size_t)(go + ti * 16 + rr) * HW + pl + tj * 16] = acc[ti][tj][rr];
}

// ---------------------------------------------------------------------------
extern "C" void kernel_launch(void* const* d_in, const int* in_sizes, int n_in,
                              void* d_out, int out_size, void* d_ws, size_t ws_size,
                              hipStream_t stream)
{
    const float* x     = (const float*)d_in[0];
    const float* wq    = (const float*)d_in[1];
    const float* wk    = (const float*)d_in[2];
    const float* wv    = (const float*)d_in[3];
    const float* pos   = (const float*)d_in[4];
    const float* wproj = (const float*)d_in[5];

    char* ws = (char*)d_ws;
    unsigned short* qkp   = (unsigned short*)ws;
    float*          vvp   = (float*)(ws + 4816896);
    unsigned short* oactp = (unsigned short*)(ws + 9633792);
    float*          outp  = (float*)d_out;

    k_p1<<<dim3(882), dim3(256), SMEM_BYTES, stream>>>(x, wq, wk, wv, qkp, vvp);
    k_p2<<<dim3(588), dim3(256), SMEM_BYTES, stream>>>(qkp, vvp, pos, oactp);
    k_p3<<<dim3(294), dim3(256), SMEM_BYTES, stream>>>(wproj, oactp, outp);
}

// Round 6
// 108.764 us; speedup vs baseline: 1.8306x; 1.0244x over previous
//
#include <hip/hip_runtime.h>

// SASA plain 3-kernel pipeline, R6: unified bf16 QKV buffer.
// B=2, CIN=192, HW=3136, 6 heads x d=32, 7x7 window.
// Cost model (calibrated R1-R5): dur_us = kernels + ~95us harness ws-poison (fixed,
// 256MiB fills at 78% HBM peak). Controllable kernel time ~16us; phase-2 is
// LDS-read-bound (~6us), phase-1 ~4-5us, phase-3 ~1.5us, gaps ~2us.
// R6 change: V stored bf16 (was fp32) in one QKV buffer -> p1 writes 12->7.2MB,
// p2 reads -2.4MB, uniform store path. vbuf stays fp32 in LDS (inner loops unchanged).
//
// ws layout (bytes):
//   QKV  [6272][576] bf16 @ 0        q ch 0-191 | k 192-383 | v 384-575
//   OACT [6272][192] bf16 @ 7225344  attention out = proj B-operand

#define HW    3136
#define WIMG  56
#define CIN   192
#define QKVLD 576
#define SMEM_BYTES 53312

using short8 = __attribute__((ext_vector_type(8))) short;
using f32x4  = __attribute__((ext_vector_type(4))) float;

__device__ __forceinline__ unsigned short f2bf(float f) {
    union { float f; unsigned u; } v; v.f = f;
    unsigned r = v.u + 0x7fffu + ((v.u >> 16) & 1u);
    return (unsigned short)(r >> 16);
}
__device__ __forceinline__ unsigned pack2(float a, float b) {
    return (unsigned)f2bf(a) | ((unsigned)f2bf(b) << 16);
}
__device__ __forceinline__ float bflo(unsigned u) {
    union { unsigned u; float f; } v; v.u = u << 16; return v.f;
}
__device__ __forceinline__ float bfhi(unsigned u) {
    union { unsigned u; float f; } v; v.u = u & 0xffff0000u; return v.f;
}

// ======================= Phase 1: QKV GEMM tile =============================
// t in [0,882): mt = t%98 (64-pixel strip over b,p), nt = t/98 (64 of 576 out ch).
// A: transpose x[b][c][p] fp32 -> As[p][c] bf16 in staging. B: W rows -> bf16.
__global__ __launch_bounds__(256) void k_p1(
    const float* __restrict__ x, const float* __restrict__ wq,
    const float* __restrict__ wk, const float* __restrict__ wv,
    unsigned short* __restrict__ qkv)
{
    extern __shared__ char smem[];
    unsigned short* As  = (unsigned short*)smem;     // 64 x 200 ushorts
    unsigned short* Bs  = As + 64 * 200;
    unsigned*       Asw = (unsigned*)smem;           // dword view, row stride 100
    unsigned*       Bsw = (unsigned*)(smem + 25600);

    const int tid = threadIdx.x;
    const int lane = tid & 63, wave = tid >> 6;
    const int l15  = lane & 15, quad = lane >> 4;
    const int wm   = (wave & 1) * 32, wn = (wave >> 1) * 32;

    const int t = blockIdx.x;
    const int mt = t % 98, nt = t / 98;
    const int m0 = mt * 64, n0 = nt * 64;
    const float* Wp = (nt < 3) ? (wq + (size_t)n0 * CIN)
                    : (nt < 6) ? (wk + (size_t)(n0 - 192) * CIN)
                               : (wv + (size_t)(n0 - 384) * CIN);

    #pragma unroll
    for (int i = 0; i < 6; ++i) {
        int u = tid + 256 * i;
        int pq = u & 15, c2 = u >> 4;            // pq: p-quad 0..15, c2: 0..95
        int pp = m0 + pq * 4;
        int bb = (pp >= HW) ? 1 : 0;
        const float* src = x + ((size_t)(bb * CIN + c2 * 2)) * HW + (pp - bb * HW);
        float4 f0 = *(const float4*)src;          // c = c2*2,   p..p+3
        float4 f1 = *(const float4*)(src + HW);   // c = c2*2+1, p..p+3
        Asw[(pq * 4 + 0) * 100 + c2] = pack2(f0.x, f1.x);
        Asw[(pq * 4 + 1) * 100 + c2] = pack2(f0.y, f1.y);
        Asw[(pq * 4 + 2) * 100 + c2] = pack2(f0.z, f1.z);
        Asw[(pq * 4 + 3) * 100 + c2] = pack2(f0.w, f1.w);
    }
    {
        int o = tid >> 2, c4 = tid & 3;
        #pragma unroll
        for (int i = 0; i < 12; ++i) {
            int cq = c4 + 4 * i;                 // 0..47
            float4 w = *(const float4*)(Wp + (size_t)o * CIN + cq * 4);
            uint2 d; d.x = pack2(w.x, w.y); d.y = pack2(w.z, w.w);
            *(uint2*)(Bsw + o * 100 + cq * 2) = d;
        }
    }
    __syncthreads();

    f32x4 acc[2][2] = {};
    const unsigned short* pa0 = As + (wm + l15) * 200 + quad * 8;
    const unsigned short* pb0 = Bs + (wn + l15) * 200 + quad * 8;
    #pragma unroll
    for (int s = 0; s < 6; ++s) {
        short8 a0 = *(const short8*)(pa0 + s * 32);
        short8 a1 = *(const short8*)(pa0 + 16 * 200 + s * 32);
        short8 b0 = *(const short8*)(pb0 + s * 32);
        short8 b1 = *(const short8*)(pb0 + 16 * 200 + s * 32);
        acc[0][0] = __builtin_amdgcn_mfma_f32_16x16x32_bf16(a0, b0, acc[0][0], 0, 0, 0);
        acc[0][1] = __builtin_amdgcn_mfma_f32_16x16x32_bf16(a0, b1, acc[0][1], 0, 0, 0);
        acc[1][0] = __builtin_amdgcn_mfma_f32_16x16x32_bf16(a1, b0, acc[1][0], 0, 0, 0);
        acc[1][1] = __builtin_amdgcn_mfma_f32_16x16x32_bf16(a1, b1, acc[1][1], 0, 0, 0);
    }

    const int gm = m0 + wm + quad * 4;   // global pixel row
    const int gn = n0 + wn + l15;        // output channel (0..575)
    #pragma unroll
    for (int ti = 0; ti < 2; ++ti)
        #pragma unroll
        for (int tj = 0; tj < 2; ++tj)
            #pragma unroll
            for (int rr = 0; rr < 4; ++rr)
                qkv[(size_t)(gm + ti * 16 + rr) * QKVLD + (gn + tj * 16)] =
                    f2bf(acc[ti][tj][rr]);
}

// ======================= Phase 2: windowed attention ========================
// t in [0,588): 49 8x8-pixel tiles x 12 (b,h). 4 threads/pixel (d split 4x8).
// K and V staged bf16->fp32 into LDS in one unified loop.
__global__ __launch_bounds__(256) void k_p2(
    const unsigned short* __restrict__ qkv, const float* __restrict__ pos,
    unsigned short* __restrict__ oact)
{
    extern __shared__ char smem[];
    float* kbuf = (float*)smem;          // [196 px][32 ch] stride 34 floats
    float* vbuf = kbuf + 6664;

    const int tid = threadIdx.x;
    const int t = blockIdx.x;
    const int tz = t / 49, r49 = t - tz * 49;
    const int ty = r49 / 7, tx = r49 - ty * 7;
    const int bq = tz / 6, h = tz - bq * 6;
    const int y0 = ty * 8 - 3, x0 = tx * 8 - 3;

    // unified K+V staging: 1568 uint4 units = 196 px * (4 k + 4 v)
    #pragma unroll
    for (int i = 0; i < 7; ++i) {
        int u = tid + 256 * i;
        if (u < 1568) {
            int pp = u >> 3, uu = u & 7;
            int part = uu >> 2, sub8 = uu & 3;       // part 0=k, 1=v
            int py = pp / 14, px = pp - py * 14;
            int gy = y0 + py, gx = x0 + px;
            float f0=0,f1=0,f2=0,f3=0,f4=0,f5=0,f6=0,f7=0;
            if ((unsigned)gy < 56u && (unsigned)gx < 56u) {
                uint4 rv = *(const uint4*)(qkv +
                    (size_t)(bq * HW + gy * WIMG + gx) * QKVLD +
                    192 + part * 192 + h * 32 + sub8 * 8);
                f0=bflo(rv.x); f1=bfhi(rv.x); f2=bflo(rv.y); f3=bfhi(rv.y);
                f4=bflo(rv.z); f5=bfhi(rv.z); f6=bflo(rv.w); f7=bfhi(rv.w);
            }
            float* dst = (part ? vbuf : kbuf) + pp * 34 + sub8 * 8;
            *(float2*)(dst + 0) = make_float2(f0, f1);
            *(float2*)(dst + 2) = make_float2(f2, f3);
            *(float2*)(dst + 4) = make_float2(f4, f5);
            *(float2*)(dst + 6) = make_float2(f6, f7);
        }
    }
    __syncthreads();

    const int sub = tid & 3, pix = tid >> 2;
    const int py = pix >> 3, px = pix & 7;
    const int y = ty * 8 + py, xx = tx * 8 + px;
    const int p = y * WIMG + xx;

    uint4 qv = *(const uint4*)(qkv + (size_t)(bq * HW + p) * QKVLD + h * 32 + sub * 8);
    float q0=bflo(qv.x), q1=bfhi(qv.x), q2=bflo(qv.y), q3=bfhi(qv.y);
    float q4=bflo(qv.z), q5=bfhi(qv.z), q6=bflo(qv.w), q7=bfhi(qv.w);

    float posr[13];
    #pragma unroll
    for (int i = 0; i < 13; ++i) posr[i] = pos[i];

    float logits[49];
    #pragma unroll
    for (int kk = 0; kk < 49; ++kk) {
        const int ky = kk / 7, kx = kk % 7;
        const int pp = (py + ky) * 14 + (px + kx);
        const float2* kp = (const float2*)(kbuf + pp * 34 + sub * 8);
        float2 k0 = kp[0], k1 = kp[1], k2 = kp[2], k3 = kp[3];
        float s = 0.f;
        s = fmaf(q0, k0.x, s); s = fmaf(q1, k0.y, s);
        s = fmaf(q2, k1.x, s); s = fmaf(q3, k1.y, s);
        s = fmaf(q4, k2.x, s); s = fmaf(q5, k2.y, s);
        s = fmaf(q6, k3.x, s); s = fmaf(q7, k3.y, s);
        s += __shfl_xor(s, 1);
        s += __shfl_xor(s, 2);
        logits[kk] = s + posr[ky + kx];
    }

    float m = logits[0];
    #pragma unroll
    for (int kk = 1; kk < 49; ++kk) m = fmaxf(m, logits[kk]);
    float sum = 0.f;
    #pragma unroll
    for (int kk = 0; kk < 49; ++kk) {
        logits[kk] = __expf(logits[kk] - m);
        sum += logits[kk];
    }
    const float inv = 1.f / sum;

    float a0=0,a1=0,a2=0,a3=0,a4=0,a5=0,a6=0,a7=0;
    #pragma unroll
    for (int kk = 0; kk < 49; ++kk) {
        const int ky = kk / 7, kx = kk % 7;
        const int pp = (py + ky) * 14 + (px + kx);
        const float2* vp = (const float2*)(vbuf + pp * 34 + sub * 8);
        float2 v0 = vp[0], v1 = vp[1], v2 = vp[2], v3 = vp[3];
        const float pw = logits[kk] * inv;
        a0 = fmaf(pw, v0.x, a0); a1 = fmaf(pw, v0.y, a1);
        a2 = fmaf(pw, v1.x, a2); a3 = fmaf(pw, v1.y, a3);
        a4 = fmaf(pw, v2.x, a4); a5 = fmaf(pw, v2.y, a5);
        a6 = fmaf(pw, v3.x, a6); a7 = fmaf(pw, v3.y, a7);
    }

    ushort4 h0, h1;
    h0.x = f2bf(a0); h0.y = f2bf(a1); h0.z = f2bf(a2); h0.w = f2bf(a3);
    h1.x = f2bf(a4); h1.y = f2bf(a5); h1.z = f2bf(a6); h1.w = f2bf(a7);
    unsigned short* ob = oact + (size_t)(bq * HW + p) * CIN + h * 32 + sub * 8;
    *(ushort4*)ob       = h0;
    *(ushort4*)(ob + 4) = h1;
}

// ======================= Phase 3: projection tile ===========================
// t in [0,294): mt = t%3 (64 out ch), pt = t/3 (64-pixel strip).
__global__ __launch_bounds__(256) void k_p3(
    const float* __restrict__ wproj, const unsigned short* __restrict__ oact,
    float* __restrict__ out)
{
    extern __shared__ char smem[];
    unsigned short* As  = (unsigned short*)smem;
    unsigned short* Bs  = As + 64 * 200;
    unsigned*       Asw = (unsigned*)smem;

    const int tid = threadIdx.x;
    const int lane = tid & 63, wave = tid >> 6;
    const int l15  = lane & 15, quad = lane >> 4;
    const int wm   = (wave & 1) * 32, wn = (wave >> 1) * 32;

    const int t = blockIdx.x;
    const int mt = t % 3, pt = t / 3;
    {
        int o = tid >> 2, c4 = tid & 3;
        #pragma unroll
        for (int i = 0; i < 12; ++i) {
            int cq = c4 + 4 * i;
            float4 w = *(const float4*)(wproj + (size_t)(mt * 64 + o) * CIN + cq * 4);
            uint2 d; d.x = pack2(w.x, w.y); d.y = pack2(w.z, w.w);
            *(uint2*)(Asw + o * 100 + cq * 2) = d;
        }
    }
    {
        int rw = tid >> 2, s4 = tid & 3;
        #pragma unroll
        for (int i = 0; i < 6; ++i) {
            int seg = s4 + 4 * i;               // 0..23
            uint4 dv = *(const uint4*)(oact + (size_t)(pt * 64 + rw) * CIN + seg * 8);
            *(uint4*)(Bs + rw * 200 + seg * 8) = dv;
        }
    }
    __syncthreads();

    f32x4 acc[2][2] = {};
    const unsigned short* pa0 = As + (wm + l15) * 200 + quad * 8;
    const unsigned short* pb0 = Bs + (wn + l15) * 200 + quad * 8;
    #pragma unroll
    for (int s = 0; s < 6; ++s) {
        short8 a0 = *(const short8*)(pa0 + s * 32);
        short8 a1 = *(const short8*)(pa0 + 16 * 200 + s * 32);
        short8 b0 = *(const short8*)(pb0 + s * 32);
        short8 b1 = *(const short8*)(pb0 + 16 * 200 + s * 32);
        acc[0][0] = __builtin_amdgcn_mfma_f32_16x16x32_bf16(a0, b0, acc[0][0], 0, 0, 0);
        acc[0][1] = __builtin_amdgcn_mfma_f32_16x16x32_bf16(a0, b1, acc[0][1], 0, 0, 0);
        acc[1][0] = __builtin_amdgcn_mfma_f32_16x16x32_bf16(a1, b0, acc[1][0], 0, 0, 0);
        acc[1][1] = __builtin_amdgcn_mfma_f32_16x16x32_bf16(a1, b1, acc[1][1], 0, 0, 0);
    }

    const int bb = (pt * 64 >= HW) ? 1 : 0;
    const int pl = pt * 64 - bb * HW + wn + l15;      // col = pixel within batch
    const int go = mt * 64 + wm + quad * 4;           // row = output channel
    float* Yb = out + (size_t)bb * (CIN * HW);
    #pragma unroll
    for (int ti = 0; ti < 2; ++ti)
        #pragma unroll
        for (int tj = 0; tj < 2; ++tj)
            #pragma unroll
            for (int rr = 0; rr < 4; ++rr)
                Yb[(size_t)(go + ti * 16 + rr) * HW + pl + tj * 16] = acc[ti][tj][rr];
}

// ---------------------------------------------------------------------------
extern "C" void kernel_launch(void* const* d_in, const int* in_sizes, int n_in,
                              void* d_out, int out_size, void* d_ws, size_t ws_size,
                              hipStream_t stream)
{
    const float* x     = (const float*)d_in[0];
    const float* wq    = (const float*)d_in[1];
    const float* wk    = (const float*)d_in[2];
    const float* wv    = (const float*)d_in[3];
    const float* pos   = (const float*)d_in[4];
    const float* wproj = (const float*)d_in[5];

    char* ws = (char*)d_ws;
    unsigned short* qkvp  = (unsigned short*)ws;
    unsigned short* oactp = (unsigned short*)(ws + 7225344);
    float*          outp  = (float*)d_out;

    k_p1<<<dim3(882), dim3(256), SMEM_BYTES, stream>>>(x, wq, wk, wv, qkvp);
    k_p2<<<dim3(588), dim3(256), SMEM_BYTES, stream>>>(qkvp, pos, oactp);
    k_p3<<<dim3(294), dim3(256), SMEM_BYTES, stream>>>(wproj, oactp, outp);
}